// Round 3
// baseline (2951.383 us; speedup 1.0000x reference)
//
#include <hip/hip_runtime.h>

#define EPS_BN 1e-5f
#define NEG_SLOPE 0.01f

// ---- degree count: in-degree over E edges (self-loops added analytically) ----
__global__ void deg_count_kernel(const int* __restrict__ dst, int* __restrict__ cnt, int E) {
    int e = blockIdx.x * blockDim.x + threadIdx.x;
    if (e < E) atomicAdd(&cnt[dst[e]], 1);
}

__global__ void dinv_kernel(const int* __restrict__ cnt, float* __restrict__ dinv, int N) {
    int i = blockIdx.x * blockDim.x + threadIdx.x;
    if (i < N) dinv[i] = rsqrtf((float)(cnt[i] + 1));   // +1 self-loop, always > 0
}

// ---- exclusive scan of cnt -> rowptr (3-kernel two-level scan) ----
__global__ void scan_block_kernel(const int* __restrict__ cnt, int* __restrict__ rowptr,
                                  int* __restrict__ bsum, int N) {
    __shared__ int s[256];
    int i = blockIdx.x * 256 + threadIdx.x;
    int v = (i < N) ? cnt[i] : 0;
    s[threadIdx.x] = v;
    __syncthreads();
    for (int off = 1; off < 256; off <<= 1) {
        int t = (threadIdx.x >= off) ? s[threadIdx.x - off] : 0;
        __syncthreads();
        s[threadIdx.x] += t;
        __syncthreads();
    }
    if (i < N) rowptr[i] = s[threadIdx.x] - v;          // exclusive
    if (threadIdx.x == 255) bsum[blockIdx.x] = s[255];
}

__global__ void scan_bsum_kernel(int* __restrict__ bsum, int nb) {
    if (threadIdx.x == 0 && blockIdx.x == 0) {
        int acc = 0;
        for (int i = 0; i < nb; ++i) { int t = bsum[i]; bsum[i] = acc; acc += t; }
    }
}

__global__ void scan_add_kernel(int* __restrict__ rowptr, const int* __restrict__ bsum, int N) {
    int i = blockIdx.x * 256 + threadIdx.x;
    if (i < N) rowptr[i] += bsum[blockIdx.x];
}

// ---- CSR fill: bucket src ids by dst ----
__global__ void csr_fill_kernel(const int* __restrict__ src, const int* __restrict__ dst,
                                const int* __restrict__ rowptr, int* __restrict__ cursor,
                                int* __restrict__ eidx, int E) {
    int e = blockIdx.x * blockDim.x + threadIdx.x;
    if (e >= E) return;
    int d = dst[e];
    int pos = atomicAdd(&cursor[d], 1);
    eidx[rowptr[d] + pos] = src[e];
}

// ---- tiny dense GEMM: T[N,Fout] = H[N,Fin] @ W[Fin,Fout], W staged in LDS ----
__global__ void gemm_kernel(const float* __restrict__ H, const float* __restrict__ W,
                            float* __restrict__ T, int N, int Fin, int Fout) {
    extern __shared__ float sW[];
    for (int i = threadIdx.x; i < Fin * Fout; i += blockDim.x) sW[i] = W[i];
    __syncthreads();
    int npb = blockDim.x / Fout;
    int node = blockIdx.x * npb + (int)(threadIdx.x / Fout);
    int f = threadIdx.x % Fout;
    if (node >= N) return;
    const float* h = H + (size_t)node * Fin;
    float acc = 0.f;
    for (int k = 0; k < Fin; ++k) acc = fmaf(h[k], sW[k * Fout + f], acc);
    T[(size_t)node * Fout + f] = acc;
}

// ---- CSR gather + self-loop + bias + BN + LeakyReLU, all fused, no atomics ----
template <int F>
__global__ void gather_fuse_kernel(const float* __restrict__ T, const int* __restrict__ rowptr,
                                   const int* __restrict__ cnt, const int* __restrict__ eidx,
                                   const float* __restrict__ dinv,
                                   const float* __restrict__ b, const float* __restrict__ gamma,
                                   const float* __restrict__ beta, const float* __restrict__ rm,
                                   const float* __restrict__ rv,
                                   float* __restrict__ h, int N) {
    int tid = blockIdx.x * blockDim.x + threadIdx.x;
    int node = tid / F;
    if (node >= N) return;
    int f = tid % F;
    int start = rowptr[node];
    int deg = cnt[node];
    float di = dinv[node];
    float acc = T[(size_t)node * F + f] * di * di;       // self-loop term
    for (int j = 0; j < deg; ++j) {
        int s = eidx[start + j];
        acc = fmaf(T[(size_t)s * F + f], dinv[s] * di, acc);
    }
    float pre = acc + b[f];
    float y = (pre - rm[f]) * rsqrtf(rv[f] + EPS_BN) * gamma[f] + beta[f];
    h[(size_t)node * F + f] = (y >= 0.f) ? y : NEG_SLOPE * y;
}

// ---- mean pool v2: batch is sorted -> register-accumulate, flush on graph change ----
#define POOL_ROWS 512
__global__ void pool_kernel2(const float* __restrict__ h, const int* __restrict__ batch,
                             float* __restrict__ out, float* __restrict__ gcnt, int N) {
    int f = threadIdx.x & 31;
    int rg = threadIdx.x >> 5;                  // 0..7
    int n0 = blockIdx.x * POOL_ROWS;
    float acc = 0.f;
    int cnt = 0, gcur = -1;
    for (int r = rg; r < POOL_ROWS; r += 8) {
        int node = n0 + r;
        if (node >= N) break;
        int g = batch[node];
        if (g != gcur) {
            if (gcur >= 0) {
                atomicAdd(&out[(gcur << 5) + f], acc);
                if (f == 0) atomicAdd(&gcnt[gcur], (float)cnt);
            }
            gcur = g; acc = 0.f; cnt = 0;
        }
        acc += h[(size_t)node * 32 + f];
        cnt++;
    }
    if (gcur >= 0) {
        atomicAdd(&out[(gcur << 5) + f], acc);
        if (f == 0) atomicAdd(&gcnt[gcur], (float)cnt);
    }
}

__global__ void pool_div_kernel(float* __restrict__ out, const float* __restrict__ gcnt, int G) {
    int tid = blockIdx.x * blockDim.x + threadIdx.x;
    if (tid < (G << 5)) out[tid] /= fmaxf(gcnt[tid >> 5], 1.0f);
}

extern "C" void kernel_launch(void* const* d_in, const int* in_sizes, int n_in,
                              void* d_out, int out_size, void* d_ws, size_t ws_size,
                              hipStream_t stream) {
    const float* x   = (const float*)d_in[0];
    const float* W1  = (const float*)d_in[1];
    const float* b1  = (const float*)d_in[2];
    const float* g1  = (const float*)d_in[3];
    const float* be1 = (const float*)d_in[4];
    const float* rm1 = (const float*)d_in[5];
    const float* rv1 = (const float*)d_in[6];
    const float* W2  = (const float*)d_in[7];
    const float* b2  = (const float*)d_in[8];
    const float* g2  = (const float*)d_in[9];
    const float* be2 = (const float*)d_in[10];
    const float* rm2 = (const float*)d_in[11];
    const float* rv2 = (const float*)d_in[12];
    const float* W3  = (const float*)d_in[13];
    const float* b3  = (const float*)d_in[14];
    const float* g3  = (const float*)d_in[15];
    const float* be3 = (const float*)d_in[16];
    const float* rm3 = (const float*)d_in[17];
    const float* rv3 = (const float*)d_in[18];
    const int* ei    = (const int*)d_in[19];
    const int* batch = (const int*)d_in[20];

    const int N = in_sizes[0] / 3;
    const int E = in_sizes[19] / 2;
    const int G = out_size / 32;
    const int* src = ei;
    const int* dst = ei + E;

    const int B = 256;
    const int nScanBlocks = (N + 255) / 256;

    // workspace layout
    int*   cnt    = (int*)d_ws;                          // N
    float* dinv   = (float*)(cnt + N);                   // N
    int*   rowptr = (int*)(dinv + N);                    // N
    int*   cursor = rowptr + N;                          // N
    int*   bsum   = cursor + N;                          // pad to 1024
    int*   eidx   = bsum + 1024;                         // E
    float* bufA   = (float*)(eidx + ((E + 3) & ~3));     // N*64 (T)
    float* bufB   = bufA + (size_t)N * 64;               // N*64 (h)
    float* gcnt   = bufB + (size_t)N * 64;               // G
    float* out    = (float*)d_out;

    // ---- degrees, dinv ----
    hipMemsetAsync(cnt, 0, (size_t)N * 4, stream);
    deg_count_kernel<<<(E + B - 1) / B, B, 0, stream>>>(dst, cnt, E);
    dinv_kernel<<<(N + B - 1) / B, B, 0, stream>>>(cnt, dinv, N);

    // ---- CSR build (reused across all 3 layers) ----
    scan_block_kernel<<<nScanBlocks, 256, 0, stream>>>(cnt, rowptr, bsum, N);
    scan_bsum_kernel<<<1, 64, 0, stream>>>(bsum, nScanBlocks);
    scan_add_kernel<<<nScanBlocks, 256, 0, stream>>>(rowptr, bsum, N);
    hipMemsetAsync(cursor, 0, (size_t)N * 4, stream);
    csr_fill_kernel<<<(E + B - 1) / B, B, 0, stream>>>(src, dst, rowptr, cursor, eidx, E);

    // ---- layer 1: x(N,3) @ W1 -> bufA; gather+BN -> bufB ----
    gemm_kernel<<<(N + 3) / 4, B, 3 * 64 * 4, stream>>>(x, W1, bufA, N, 3, 64);
    gather_fuse_kernel<64><<<(int)(((size_t)N * 64 + B - 1) / B), B, 0, stream>>>(
        bufA, rowptr, cnt, eidx, dinv, b1, g1, be1, rm1, rv1, bufB, N);

    // ---- layer 2 ----
    gemm_kernel<<<(N + 3) / 4, B, 64 * 64 * 4, stream>>>(bufB, W2, bufA, N, 64, 64);
    gather_fuse_kernel<64><<<(int)(((size_t)N * 64 + B - 1) / B), B, 0, stream>>>(
        bufA, rowptr, cnt, eidx, dinv, b2, g2, be2, rm2, rv2, bufB, N);

    // ---- layer 3 ----
    gemm_kernel<<<(N + 7) / 8, B, 64 * 32 * 4, stream>>>(bufB, W3, bufA, N, 64, 32);
    gather_fuse_kernel<32><<<(int)(((size_t)N * 32 + B - 1) / B), B, 0, stream>>>(
        bufA, rowptr, cnt, eidx, dinv, b3, g3, be3, rm3, rv3, bufB, N);

    // ---- mean pool ----
    hipMemsetAsync(out, 0, (size_t)G * 32 * 4, stream);
    hipMemsetAsync(gcnt, 0, (size_t)G * 4, stream);
    pool_kernel2<<<(N + POOL_ROWS - 1) / POOL_ROWS, 256, 0, stream>>>(bufB, batch, out, gcnt, N);
    pool_div_kernel<<<(G * 32 + B - 1) / B, B, 0, stream>>>(out, gcnt, G);
}

// Round 4
// 455.672 us; speedup vs baseline: 6.4770x; 6.4770x over previous
//
#include <hip/hip_runtime.h>

#define EPS_BN 1e-5f
#define NEG_SLOPE 0.01f

// ---- bf16x2 pack/unpack (RNE) ----
__device__ __forceinline__ uint32_t pack2_bf16(float x, float y) {
    uint32_t ux = __float_as_uint(x);
    uint32_t uy = __float_as_uint(y);
    ux = (ux + 0x7fffu + ((ux >> 16) & 1u)) >> 16;
    uy = (uy + 0x7fffu + ((uy >> 16) & 1u)) >> 16;
    return (uy << 16) | (ux & 0xffffu);
}
__device__ __forceinline__ float bf_lo(uint32_t p) { return __uint_as_float(p << 16); }
__device__ __forceinline__ float bf_hi(uint32_t p) { return __uint_as_float(p & 0xffff0000u); }

// ---- degree count: in-degree over E edges (self-loops added analytically) ----
__global__ void deg_count_kernel(const int* __restrict__ dst, int* __restrict__ cnt, int E) {
    int e = blockIdx.x * blockDim.x + threadIdx.x;
    if (e < E) atomicAdd(&cnt[dst[e]], 1);
}

// ---- block-level exclusive scan of cnt -> rowptr; also emits dinv ----
__global__ void scan_block_kernel(const int* __restrict__ cnt, int* __restrict__ rowptr,
                                  int* __restrict__ bsum, float* __restrict__ dinv, int N) {
    __shared__ int s[256];
    int i = blockIdx.x * 256 + threadIdx.x;
    int v = (i < N) ? cnt[i] : 0;
    if (i < N) dinv[i] = rsqrtf((float)(v + 1));        // +1 self-loop, always > 0
    s[threadIdx.x] = v;
    __syncthreads();
    for (int off = 1; off < 256; off <<= 1) {
        int t = (threadIdx.x >= off) ? s[threadIdx.x - off] : 0;
        __syncthreads();
        s[threadIdx.x] += t;
        __syncthreads();
    }
    if (i < N) rowptr[i] = s[threadIdx.x] - v;          // exclusive
    if (threadIdx.x == 255) bsum[blockIdx.x] = s[255];
}

// ---- single-block parallel scan of block sums (chunked, carries across chunks) ----
__global__ void scan_bsum_kernel(int* __restrict__ bsum, int nb) {
    __shared__ int s[512];
    __shared__ int carry;
    if (threadIdx.x == 0) carry = 0;
    __syncthreads();
    for (int base = 0; base < nb; base += 512) {
        int i = base + threadIdx.x;
        int v = (i < nb) ? bsum[i] : 0;
        s[threadIdx.x] = v;
        __syncthreads();
        for (int off = 1; off < 512; off <<= 1) {
            int t = (threadIdx.x >= off) ? s[threadIdx.x - off] : 0;
            __syncthreads();
            s[threadIdx.x] += t;
            __syncthreads();
        }
        int c = carry;
        if (i < nb) bsum[i] = s[threadIdx.x] - v + c;   // exclusive + carry
        __syncthreads();
        if (threadIdx.x == 0) carry = c + s[511];
        __syncthreads();
    }
}

// ---- propagate block offsets; also zero out/gcnt (saves two memsets) ----
__global__ void scan_add_kernel(int* __restrict__ rowptr, const int* __restrict__ bsum, int N,
                                float* __restrict__ out, float* __restrict__ gcnt, int G) {
    int i = blockIdx.x * 256 + threadIdx.x;
    if (i < N) rowptr[i] += bsum[blockIdx.x];
    if (i < G * 32) out[i] = 0.f;
    if (i < G) gcnt[i] = 0.f;
}

// ---- CSR fill: edge record = {src, norm=dinv[s]*dinv[d]} ----
__global__ void csr_fill_kernel(const int* __restrict__ src, const int* __restrict__ dst,
                                const int* __restrict__ rowptr, int* __restrict__ cursor,
                                const float* __restrict__ dinv, int2* __restrict__ edges, int E) {
    int e = blockIdx.x * blockDim.x + threadIdx.x;
    if (e >= E) return;
    int s = src[e], d = dst[e];
    int pos = atomicAdd(&cursor[d], 1);
    float nrm = dinv[s] * dinv[d];
    edges[rowptr[d] + pos] = make_int2(s, __float_as_int(nrm));
}

// ---- dense GEMM: Tp[N, FOUT/2] (bf16x2) = H[N,FIN] @ W[FIN,FOUT]; W in LDS ----
template <int FIN, int FOUT>
__global__ void gemm_pack_kernel(const float* __restrict__ H, const float* __restrict__ W,
                                 uint32_t* __restrict__ Tp, int N) {
    constexpr int TPN = FOUT / 2;                       // threads per node
    constexpr int NPB = 256 / TPN;                      // nodes per block
    __shared__ float sW[FIN * FOUT];
    for (int i = threadIdx.x; i < FIN * FOUT; i += 256) sW[i] = W[i];
    __syncthreads();
    int node = blockIdx.x * NPB + (int)(threadIdx.x / TPN);
    int f2 = threadIdx.x % TPN;
    if (node >= N) return;
    const float* h = H + (size_t)node * FIN;
    const float2* w2 = (const float2*)sW + f2;          // stride FOUT/2 float2 per k
    float a0 = 0.f, a1 = 0.f;
    int k = 0;
    for (; k + 4 <= FIN; k += 4) {
        float4 hv = *(const float4*)(h + k);            // broadcast within node group
        float2 w;
        w = w2[(k + 0) * TPN]; a0 = fmaf(hv.x, w.x, a0); a1 = fmaf(hv.x, w.y, a1);
        w = w2[(k + 1) * TPN]; a0 = fmaf(hv.y, w.x, a0); a1 = fmaf(hv.y, w.y, a1);
        w = w2[(k + 2) * TPN]; a0 = fmaf(hv.z, w.x, a0); a1 = fmaf(hv.z, w.y, a1);
        w = w2[(k + 3) * TPN]; a0 = fmaf(hv.w, w.x, a0); a1 = fmaf(hv.w, w.y, a1);
    }
    for (; k < FIN; ++k) {
        float hv = h[k];
        float2 w = w2[k * TPN];
        a0 = fmaf(hv, w.x, a0); a1 = fmaf(hv, w.y, a1);
    }
    Tp[(size_t)node * TPN + f2] = pack2_bf16(a0, a1);
}

// ---- CSR gather (bf16 rows) + self-loop + bias + BN + LeakyReLU, fused ----
template <int F>
__global__ void gather_fuse_kernel(const uint32_t* __restrict__ Tp, const int* __restrict__ rowptr,
                                   const int* __restrict__ cnt, const int2* __restrict__ edges,
                                   const float* __restrict__ dinv,
                                   const float* __restrict__ b, const float* __restrict__ gamma,
                                   const float* __restrict__ beta, const float* __restrict__ rm,
                                   const float* __restrict__ rv,
                                   float* __restrict__ h, int N) {
    constexpr int TPN = F / 2;
    int tid = blockIdx.x * blockDim.x + threadIdx.x;
    int node = tid / TPN;
    if (node >= N) return;
    int f2 = tid % TPN;
    int start = rowptr[node];
    int deg = cnt[node];
    float di = dinv[node];
    uint32_t tself = Tp[(size_t)node * TPN + f2];
    float a0 = bf_lo(tself) * di * di;                  // self-loop term
    float a1 = bf_hi(tself) * di * di;
    const int2* ep = edges + start;
    int2 nxt = (deg > 0) ? ep[0] : make_int2(0, 0);     // software pipeline edge record
    for (int j = 0; j < deg; ++j) {
        int2 cur = nxt;
        if (j + 1 < deg) nxt = ep[j + 1];
        float nrm = __int_as_float(cur.y);
        uint32_t tv = Tp[(size_t)cur.x * TPN + f2];
        a0 = fmaf(bf_lo(tv), nrm, a0);
        a1 = fmaf(bf_hi(tv), nrm, a1);
    }
    int f0 = 2 * f2, f1 = f0 + 1;
    float p0 = a0 + b[f0], p1 = a1 + b[f1];
    float y0 = (p0 - rm[f0]) * rsqrtf(rv[f0] + EPS_BN) * gamma[f0] + beta[f0];
    float y1 = (p1 - rm[f1]) * rsqrtf(rv[f1] + EPS_BN) * gamma[f1] + beta[f1];
    float2 o;
    o.x = (y0 >= 0.f) ? y0 : NEG_SLOPE * y0;
    o.y = (y1 >= 0.f) ? y1 : NEG_SLOPE * y1;
    *(float2*)(h + (size_t)node * F + f0) = o;
}

// ---- mean pool: batch sorted -> register-accumulate, flush on graph change ----
#define POOL_ROWS 128
__global__ void pool_kernel2(const float* __restrict__ h, const int* __restrict__ batch,
                             float* __restrict__ out, float* __restrict__ gcnt, int N) {
    int f = threadIdx.x & 31;
    int rg = threadIdx.x >> 5;                          // 0..7
    int n0 = blockIdx.x * POOL_ROWS;
    float acc = 0.f;
    int cnt = 0, gcur = -1;
    for (int r = rg; r < POOL_ROWS; r += 8) {
        int node = n0 + r;
        if (node >= N) break;
        int g = batch[node];
        if (g != gcur) {
            if (gcur >= 0) {
                atomicAdd(&out[(gcur << 5) + f], acc);
                if (f == 0) atomicAdd(&gcnt[gcur], (float)cnt);
            }
            gcur = g; acc = 0.f; cnt = 0;
        }
        acc += h[(size_t)node * 32 + f];
        cnt++;
    }
    if (gcur >= 0) {
        atomicAdd(&out[(gcur << 5) + f], acc);
        if (f == 0) atomicAdd(&gcnt[gcur], (float)cnt);
    }
}

__global__ void pool_div_kernel(float* __restrict__ out, const float* __restrict__ gcnt, int G) {
    int tid = blockIdx.x * blockDim.x + threadIdx.x;
    if (tid < (G << 5)) out[tid] /= fmaxf(gcnt[tid >> 5], 1.0f);
}

extern "C" void kernel_launch(void* const* d_in, const int* in_sizes, int n_in,
                              void* d_out, int out_size, void* d_ws, size_t ws_size,
                              hipStream_t stream) {
    const float* x   = (const float*)d_in[0];
    const float* W1  = (const float*)d_in[1];
    const float* b1  = (const float*)d_in[2];
    const float* g1  = (const float*)d_in[3];
    const float* be1 = (const float*)d_in[4];
    const float* rm1 = (const float*)d_in[5];
    const float* rv1 = (const float*)d_in[6];
    const float* W2  = (const float*)d_in[7];
    const float* b2  = (const float*)d_in[8];
    const float* g2  = (const float*)d_in[9];
    const float* be2 = (const float*)d_in[10];
    const float* rm2 = (const float*)d_in[11];
    const float* rv2 = (const float*)d_in[12];
    const float* W3  = (const float*)d_in[13];
    const float* b3  = (const float*)d_in[14];
    const float* g3  = (const float*)d_in[15];
    const float* be3 = (const float*)d_in[16];
    const float* rm3 = (const float*)d_in[17];
    const float* rv3 = (const float*)d_in[18];
    const int* ei    = (const int*)d_in[19];
    const int* batch = (const int*)d_in[20];

    const int N = in_sizes[0] / 3;
    const int E = in_sizes[19] / 2;
    const int G = out_size / 32;
    const int* src = ei;
    const int* dst = ei + E;

    const int B = 256;
    const int nScanBlocks = (N + 255) / 256;

    // workspace layout
    int*      cnt    = (int*)d_ws;                       // N
    int*      cursor = cnt + N;                          // N (zeroed together with cnt)
    float*    dinv   = (float*)(cursor + N);             // N
    int*      rowptr = (int*)(dinv + N);                 // N
    int*      bsum   = rowptr + N;                       // 1024 pad
    int2*     edges  = (int2*)(((uintptr_t)(bsum + 1024) + 15) & ~(uintptr_t)15);  // E int2
    uint32_t* Tp     = (uint32_t*)(edges + E);           // N*32 (bf16x2, max FOUT=64)
    float*    hbuf   = (float*)(Tp + (size_t)N * 32);    // N*64
    float*    gcnt   = hbuf + (size_t)N * 64;            // G
    float*    out    = (float*)d_out;

    // ---- degrees ----
    hipMemsetAsync(cnt, 0, (size_t)2 * N * 4, stream);   // cnt + cursor
    deg_count_kernel<<<(E + B - 1) / B, B, 0, stream>>>(dst, cnt, E);

    // ---- CSR build (reused by all 3 layers); dinv + out/gcnt zero fused in ----
    scan_block_kernel<<<nScanBlocks, 256, 0, stream>>>(cnt, rowptr, bsum, dinv, N);
    scan_bsum_kernel<<<1, 512, 0, stream>>>(bsum, nScanBlocks);
    scan_add_kernel<<<nScanBlocks, 256, 0, stream>>>(rowptr, bsum, N, out, gcnt, G);
    csr_fill_kernel<<<(E + B - 1) / B, B, 0, stream>>>(src, dst, rowptr, cursor, dinv, edges, E);

    // ---- layer 1: x(N,3) @ W1 -> Tp(bf16); gather+BN -> hbuf ----
    gemm_pack_kernel<3, 64><<<(N + 7) / 8, 256, 0, stream>>>(x, W1, Tp, N);
    gather_fuse_kernel<64><<<(int)(((size_t)N * 32 + B - 1) / B), B, 0, stream>>>(
        Tp, rowptr, cnt, edges, dinv, b1, g1, be1, rm1, rv1, hbuf, N);

    // ---- layer 2 ----
    gemm_pack_kernel<64, 64><<<(N + 7) / 8, 256, 0, stream>>>(hbuf, W2, Tp, N);
    gather_fuse_kernel<64><<<(int)(((size_t)N * 32 + B - 1) / B), B, 0, stream>>>(
        Tp, rowptr, cnt, edges, dinv, b2, g2, be2, rm2, rv2, hbuf, N);

    // ---- layer 3 ----
    gemm_pack_kernel<64, 32><<<(N + 15) / 16, 256, 0, stream>>>(hbuf, W3, Tp, N);
    gather_fuse_kernel<32><<<(int)(((size_t)N * 16 + B - 1) / B), B, 0, stream>>>(
        Tp, rowptr, cnt, edges, dinv, b3, g3, be3, rm3, rv3, hbuf, N);

    // ---- mean pool ----
    pool_kernel2<<<(N + POOL_ROWS - 1) / POOL_ROWS, 256, 0, stream>>>(hbuf, batch, out, gcnt, N);
    pool_div_kernel<<<(G * 32 + B - 1) / B, B, 0, stream>>>(out, gcnt, G);
}

// Round 5
// 396.543 us; speedup vs baseline: 7.4428x; 1.1491x over previous
//
#include <hip/hip_runtime.h>

#define EPS_BN 1e-5f
#define NEG_SLOPE 0.01f

// ---- bf16x2 pack/unpack (RNE) ----
__device__ __forceinline__ uint32_t pack2_bf16(float x, float y) {
    uint32_t ux = __float_as_uint(x);
    uint32_t uy = __float_as_uint(y);
    ux = (ux + 0x7fffu + ((ux >> 16) & 1u)) >> 16;
    uy = (uy + 0x7fffu + ((uy >> 16) & 1u)) >> 16;
    return (uy << 16) | (ux & 0xffffu);
}
__device__ __forceinline__ float bf_lo(uint32_t p) { return __uint_as_float(p << 16); }
__device__ __forceinline__ float bf_hi(uint32_t p) { return __uint_as_float(p & 0xffff0000u); }

// ---- degree count ----
__global__ void deg_count_kernel(const int* __restrict__ dst, int* __restrict__ cnt, int E) {
    int e = blockIdx.x * blockDim.x + threadIdx.x;
    if (e < E) atomicAdd(&cnt[dst[e]], 1);
}

// ---- block scan of cnt -> rowptr; emits dinv and xs = x*dinv (float4, pad) ----
__global__ void scan_block_kernel(const int* __restrict__ cnt, int* __restrict__ rowptr,
                                  int* __restrict__ bsum, float* __restrict__ dinv,
                                  const float* __restrict__ x, float4* __restrict__ xs, int N) {
    __shared__ int s[256];
    int i = blockIdx.x * 256 + threadIdx.x;
    int v = (i < N) ? cnt[i] : 0;
    if (i < N) {
        float di = rsqrtf((float)(v + 1));              // +1 self-loop, always > 0
        dinv[i] = di;
        const float* xr = x + (size_t)i * 3;
        xs[i] = make_float4(xr[0] * di, xr[1] * di, xr[2] * di, 0.f);
    }
    s[threadIdx.x] = v;
    __syncthreads();
    for (int off = 1; off < 256; off <<= 1) {
        int t = (threadIdx.x >= off) ? s[threadIdx.x - off] : 0;
        __syncthreads();
        s[threadIdx.x] += t;
        __syncthreads();
    }
    if (i < N) rowptr[i] = s[threadIdx.x] - v;          // exclusive
    if (threadIdx.x == 255) bsum[blockIdx.x] = s[255];
}

// ---- single-block chunked scan of block sums ----
__global__ void scan_bsum_kernel(int* __restrict__ bsum, int nb) {
    __shared__ int s[512];
    __shared__ int carry;
    if (threadIdx.x == 0) carry = 0;
    __syncthreads();
    for (int base = 0; base < nb; base += 512) {
        int i = base + threadIdx.x;
        int v = (i < nb) ? bsum[i] : 0;
        s[threadIdx.x] = v;
        __syncthreads();
        for (int off = 1; off < 512; off <<= 1) {
            int t = (threadIdx.x >= off) ? s[threadIdx.x - off] : 0;
            __syncthreads();
            s[threadIdx.x] += t;
            __syncthreads();
        }
        int c = carry;
        if (i < nb) bsum[i] = s[threadIdx.x] - v + c;
        __syncthreads();
        if (threadIdx.x == 0) carry = c + s[511];
        __syncthreads();
    }
}

// ---- propagate block offsets; also zero out/gcnt ----
__global__ void scan_add_kernel(int* __restrict__ rowptr, const int* __restrict__ bsum, int N,
                                float* __restrict__ out, float* __restrict__ gcnt, int G) {
    int i = blockIdx.x * 256 + threadIdx.x;
    if (i < N) rowptr[i] += bsum[blockIdx.x];
    if (i < G * 32) out[i] = 0.f;
    if (i < G) gcnt[i] = 0.f;
}

// ---- CSR fill: 4-byte record = src only (norm folded into row scaling) ----
__global__ void csr_fill_kernel(const int* __restrict__ src, const int* __restrict__ dst,
                                const int* __restrict__ rowptr, int* __restrict__ cursor,
                                int* __restrict__ eidx, int E) {
    int e = blockIdx.x * blockDim.x + threadIdx.x;
    if (e >= E) return;
    int d = dst[e];
    int pos = atomicAdd(&cursor[d], 1);
    eidx[rowptr[d] + pos] = src[e];
}

// ---- layer-1 gather on raw features: agg[n] = dinv[n]*(sum xs[s] + xs[n]) ----
__global__ void gather_x_kernel(const float* __restrict__ xs, const int* __restrict__ rowptr,
                                const int* __restrict__ cnt, const int* __restrict__ eidx,
                                const float* __restrict__ dinv, float* __restrict__ agg, int N) {
    int tid = blockIdx.x * blockDim.x + threadIdx.x;
    int node = tid >> 2;
    if (node >= N) return;
    int f = tid & 3;
    int start = rowptr[node];
    int deg = cnt[node];
    float acc = xs[4 * (size_t)node + f];               // self (already *dinv[node])
    const int* ep = eidx + start;
    int j = 0;
    float acc2 = 0.f;
    for (; j + 2 <= deg; j += 2) {
        int s0 = ep[j], s1 = ep[j + 1];
        acc  += xs[4 * (size_t)s0 + f];
        acc2 += xs[4 * (size_t)s1 + f];
    }
    if (j < deg) acc += xs[4 * (size_t)ep[j] + f];
    agg[4 * (size_t)node + f] = (acc + acc2) * dinv[node];
}

// ---- GEMM1 (3->64) + bias + BN + LeakyReLU fused, fp32 out ----
__global__ void gemm1_bn_kernel(const float4* __restrict__ agg, const float* __restrict__ W,
                                const float* __restrict__ b, const float* __restrict__ gamma,
                                const float* __restrict__ beta, const float* __restrict__ rm,
                                const float* __restrict__ rv, float* __restrict__ h, int N) {
    __shared__ float sW[3 * 64];
    __shared__ float sScale[64], sShift[64];
    if (threadIdx.x < 3 * 64) sW[threadIdx.x] = W[threadIdx.x];
    if (threadIdx.x < 64) {
        int f = threadIdx.x;
        float sc = rsqrtf(rv[f] + EPS_BN) * gamma[f];
        sScale[f] = sc;
        sShift[f] = (b[f] - rm[f]) * sc + beta[f];
    }
    __syncthreads();
    int node = blockIdx.x * 8 + (int)(threadIdx.x >> 5);
    if (node >= N) return;
    int f0 = (threadIdx.x & 31) * 2, f1 = f0 + 1;
    float4 av = agg[node];
    float a0 = av.x * sW[f0] + av.y * sW[64 + f0] + av.z * sW[128 + f0];
    float a1 = av.x * sW[f1] + av.y * sW[64 + f1] + av.z * sW[128 + f1];
    float y0 = a0 * sScale[f0] + sShift[f0];
    float y1 = a1 * sScale[f1] + sShift[f1];
    float2 o;
    o.x = (y0 >= 0.f) ? y0 : NEG_SLOPE * y0;
    o.y = (y1 >= 0.f) ? y1 : NEG_SLOPE * y1;
    *(float2*)(h + (size_t)node * 64 + f0) = o;
}

// ---- dense GEMM + dinv row-scale + bf16 pack: Tp[n] = (H[n]@W)*dinv[n] ----
template <int FIN, int FOUT>
__global__ void gemm_pack_scale_kernel(const float* __restrict__ H, const float* __restrict__ W,
                                       const float* __restrict__ dinv, uint32_t* __restrict__ Tp,
                                       int N) {
    constexpr int TPN = FOUT / 2;
    constexpr int NPB = 256 / TPN;
    __shared__ float sW[FIN * FOUT];
    for (int i = threadIdx.x; i < FIN * FOUT; i += 256) sW[i] = W[i];
    __syncthreads();
    int node = blockIdx.x * NPB + (int)(threadIdx.x / TPN);
    int f2 = threadIdx.x % TPN;
    if (node >= N) return;
    const float* h = H + (size_t)node * FIN;
    const float2* w2 = (const float2*)sW + f2;
    float a0 = 0.f, a1 = 0.f;
    for (int k = 0; k + 4 <= FIN; k += 4) {
        float4 hv = *(const float4*)(h + k);
        float2 w;
        w = w2[(k + 0) * TPN]; a0 = fmaf(hv.x, w.x, a0); a1 = fmaf(hv.x, w.y, a1);
        w = w2[(k + 1) * TPN]; a0 = fmaf(hv.y, w.x, a0); a1 = fmaf(hv.y, w.y, a1);
        w = w2[(k + 2) * TPN]; a0 = fmaf(hv.z, w.x, a0); a1 = fmaf(hv.z, w.y, a1);
        w = w2[(k + 3) * TPN]; a0 = fmaf(hv.w, w.x, a0); a1 = fmaf(hv.w, w.y, a1);
    }
    float di = dinv[node];
    Tp[(size_t)node * TPN + f2] = pack2_bf16(a0 * di, a1 * di);
}

// ---- CSR gather (scaled bf16 rows, 4B edge records) + BN + LeakyReLU ----
template <int F>
__global__ void gather_fuse_kernel(const uint32_t* __restrict__ Tp, const int* __restrict__ rowptr,
                                   const int* __restrict__ cnt, const int* __restrict__ eidx,
                                   const float* __restrict__ dinv,
                                   const float* __restrict__ b, const float* __restrict__ gamma,
                                   const float* __restrict__ beta, const float* __restrict__ rm,
                                   const float* __restrict__ rv,
                                   float* __restrict__ h, int N) {
    constexpr int TPN = F / 2;
    int tid = blockIdx.x * blockDim.x + threadIdx.x;
    int node = tid / TPN;
    if (node >= N) return;
    int f2 = tid % TPN;
    int start = rowptr[node];
    int deg = cnt[node];
    uint32_t tself = Tp[(size_t)node * TPN + f2];
    float a0 = bf_lo(tself), a1 = bf_hi(tself);         // self term (rows pre-scaled)
    float c0 = 0.f, c1 = 0.f;
    const int* ep = eidx + start;
    int j = 0;
    for (; j + 2 <= deg; j += 2) {
        int s0 = ep[j], s1 = ep[j + 1];
        uint32_t t0 = Tp[(size_t)s0 * TPN + f2];
        uint32_t t1 = Tp[(size_t)s1 * TPN + f2];
        a0 += bf_lo(t0); a1 += bf_hi(t0);
        c0 += bf_lo(t1); c1 += bf_hi(t1);
    }
    if (j < deg) {
        uint32_t t0 = Tp[(size_t)ep[j] * TPN + f2];
        a0 += bf_lo(t0); a1 += bf_hi(t0);
    }
    float di = dinv[node];
    int f0 = 2 * f2, f1 = f0 + 1;
    float sc0 = rsqrtf(rv[f0] + EPS_BN) * gamma[f0];
    float sc1 = rsqrtf(rv[f1] + EPS_BN) * gamma[f1];
    float y0 = (a0 + c0) * di * sc0 + (b[f0] - rm[f0]) * sc0 + beta[f0];
    float y1 = (a1 + c1) * di * sc1 + (b[f1] - rm[f1]) * sc1 + beta[f1];
    float2 o;
    o.x = (y0 >= 0.f) ? y0 : NEG_SLOPE * y0;
    o.y = (y1 >= 0.f) ? y1 : NEG_SLOPE * y1;
    *(float2*)(h + (size_t)node * F + f0) = o;
}

// ---- mean pool: batch sorted -> register-accumulate, flush on graph change ----
#define POOL_ROWS 128
__global__ void pool_kernel2(const float* __restrict__ h, const int* __restrict__ batch,
                             float* __restrict__ out, float* __restrict__ gcnt, int N) {
    int f = threadIdx.x & 31;
    int rg = threadIdx.x >> 5;
    int n0 = blockIdx.x * POOL_ROWS;
    float acc = 0.f;
    int cnt = 0, gcur = -1;
    for (int r = rg; r < POOL_ROWS; r += 8) {
        int node = n0 + r;
        if (node >= N) break;
        int g = batch[node];
        if (g != gcur) {
            if (gcur >= 0) {
                atomicAdd(&out[(gcur << 5) + f], acc);
                if (f == 0) atomicAdd(&gcnt[gcur], (float)cnt);
            }
            gcur = g; acc = 0.f; cnt = 0;
        }
        acc += h[(size_t)node * 32 + f];
        cnt++;
    }
    if (gcur >= 0) {
        atomicAdd(&out[(gcur << 5) + f], acc);
        if (f == 0) atomicAdd(&gcnt[gcur], (float)cnt);
    }
}

__global__ void pool_div_kernel(float* __restrict__ out, const float* __restrict__ gcnt, int G) {
    int tid = blockIdx.x * blockDim.x + threadIdx.x;
    if (tid < (G << 5)) out[tid] /= fmaxf(gcnt[tid >> 5], 1.0f);
}

extern "C" void kernel_launch(void* const* d_in, const int* in_sizes, int n_in,
                              void* d_out, int out_size, void* d_ws, size_t ws_size,
                              hipStream_t stream) {
    const float* x   = (const float*)d_in[0];
    const float* W1  = (const float*)d_in[1];
    const float* b1  = (const float*)d_in[2];
    const float* g1  = (const float*)d_in[3];
    const float* be1 = (const float*)d_in[4];
    const float* rm1 = (const float*)d_in[5];
    const float* rv1 = (const float*)d_in[6];
    const float* W2  = (const float*)d_in[7];
    const float* b2  = (const float*)d_in[8];
    const float* g2  = (const float*)d_in[9];
    const float* be2 = (const float*)d_in[10];
    const float* rm2 = (const float*)d_in[11];
    const float* rv2 = (const float*)d_in[12];
    const float* W3  = (const float*)d_in[13];
    const float* b3  = (const float*)d_in[14];
    const float* g3  = (const float*)d_in[15];
    const float* be3 = (const float*)d_in[16];
    const float* rm3 = (const float*)d_in[17];
    const float* rv3 = (const float*)d_in[18];
    const int* ei    = (const int*)d_in[19];
    const int* batch = (const int*)d_in[20];

    const int N = in_sizes[0] / 3;
    const int E = in_sizes[19] / 2;
    const int G = out_size / 32;
    const int* src = ei;
    const int* dst = ei + E;

    const int B = 256;
    const int nScanBlocks = (N + 255) / 256;

    // workspace layout
    int*      cnt    = (int*)d_ws;                         // N
    int*      cursor = cnt + N;                            // N (zeroed with cnt)
    float*    dinv   = (float*)(cursor + N);               // N
    int*      rowptr = (int*)(dinv + N);                   // N
    int*      bsum   = rowptr + N;                         // 1024 pad
    int*      eidx   = bsum + 1024;                        // E ints
    float4*   xs     = (float4*)(((uintptr_t)(eidx + E) + 15) & ~(uintptr_t)15);  // N float4
    float*    agg1   = (float*)(xs + N);                   // N*4
    uint32_t* Tp     = (uint32_t*)(agg1 + (size_t)N * 4);  // N*32 (bf16x2, max FOUT=64)
    float*    hbuf   = (float*)(Tp + (size_t)N * 32);      // N*64
    float*    gcnt   = hbuf + (size_t)N * 64;              // G
    float*    out    = (float*)d_out;

    // ---- degrees ----
    hipMemsetAsync(cnt, 0, (size_t)2 * N * 4, stream);     // cnt + cursor
    deg_count_kernel<<<(E + B - 1) / B, B, 0, stream>>>(dst, cnt, E);

    // ---- CSR build + dinv + xs; out/gcnt zero fused in ----
    scan_block_kernel<<<nScanBlocks, 256, 0, stream>>>(cnt, rowptr, bsum, dinv, x, xs, N);
    scan_bsum_kernel<<<1, 512, 0, stream>>>(bsum, nScanBlocks);
    scan_add_kernel<<<nScanBlocks, 256, 0, stream>>>(rowptr, bsum, N, out, gcnt, G);
    csr_fill_kernel<<<(E + B - 1) / B, B, 0, stream>>>(src, dst, rowptr, cursor, eidx, E);

    // ---- layer 1 (aggregate-first): agg1 = A_norm @ x ; then GEMM+BN fused ----
    gather_x_kernel<<<(int)(((size_t)N * 4 + B - 1) / B), B, 0, stream>>>(
        (const float*)xs, rowptr, cnt, eidx, dinv, agg1, N);
    gemm1_bn_kernel<<<(N + 7) / 8, 256, 0, stream>>>(
        (const float4*)agg1, W1, b1, g1, be1, rm1, rv1, hbuf, N);

    // ---- layer 2 ----
    gemm_pack_scale_kernel<64, 64><<<(N + 7) / 8, 256, 0, stream>>>(hbuf, W2, dinv, Tp, N);
    gather_fuse_kernel<64><<<(int)(((size_t)N * 32 + B - 1) / B), B, 0, stream>>>(
        Tp, rowptr, cnt, eidx, dinv, b2, g2, be2, rm2, rv2, hbuf, N);

    // ---- layer 3 ----
    gemm_pack_scale_kernel<64, 32><<<(N + 15) / 16, 256, 0, stream>>>(hbuf, W3, dinv, Tp, N);
    gather_fuse_kernel<32><<<(int)(((size_t)N * 16 + B - 1) / B), B, 0, stream>>>(
        Tp, rowptr, cnt, eidx, dinv, b3, g3, be3, rm3, rv3, hbuf, N);

    // ---- mean pool ----
    pool_kernel2<<<(N + POOL_ROWS - 1) / POOL_ROWS, 256, 0, stream>>>(hbuf, batch, out, gcnt, N);
    pool_div_kernel<<<(G * 32 + B - 1) / B, B, 0, stream>>>(out, gcnt, G);
}